// Round 11
// baseline (278.473 us; speedup 1.0000x reference)
//
#include <hip/hip_runtime.h>

// Masked scatter-mean, 3-kernel pipeline (no float atomics anywhere).
// R11: (1) bin_fixed at 512thr/TILE4096 -> 4 blocks/CU (phase overlap);
//      (2) sort_gather scan via wave shuffles (3 barriers, was 20);
//      (3) nt FULL-LINE out store (isolated A/B for L3 steering).
//   init_bcur   : bcur[b] = b*CAP
//   bin_fixed   : ONE edge pass (nt loads); LDS hist; reserve ranges; plain
//                 cached scattered writes of packed (src<<10 | tgt&1023)
//   sort_gather : per-bucket LDS sort + predicated 8-deep register gather
// Fallback: R1 atomic path if ws too small / shapes out of range.

#define CCH 32
#define BSH 10            // 1024 targets per bucket
#define BKT 1024
#define CAP 8960          // slots per bucket window (mean fill ~7373, +18 sigma)
#define BIN_THREADS 512
#define BIN_TILE 4096
typedef unsigned int u32;
typedef float f32x4 __attribute__((ext_vector_type(4)));

__global__ __launch_bounds__(256) void init_bcur_kernel(u32* __restrict__ bcur,
                                                        int NB) {
  int i = blockIdx.x * 256 + threadIdx.x;
  if (i < NB) bcur[i] = (u32)i * (u32)CAP;
}

__global__ __launch_bounds__(BIN_THREADS) void bin_fixed_kernel(
    const int* __restrict__ src_ids, const int* __restrict__ tgt_ids,
    const int* __restrict__ ntypes, u32* __restrict__ bcur,
    u32* __restrict__ pairs, int E, int NB) {
  __shared__ unsigned short s_b[BIN_TILE];  // bucket id (0xFFFF = invalid)
  __shared__ u32 s_pw[BIN_TILE];            // packed (src<<10 | local_tgt)
  __shared__ u32 s_cnt[2048];
  __shared__ u32 s_base[2048];
  const long long base = (long long)blockIdx.x * BIN_TILE;

  for (int j = threadIdx.x; j < 2048; j += BIN_THREADS) s_cnt[j] = 0;
  __syncthreads();

  // merged load + histogram pass (nt loads: stream-once edge data)
  for (int k = 0; k < BIN_TILE / BIN_THREADS; ++k) {
    const int i = threadIdx.x + k * BIN_THREADS;
    const long long e = base + i;
    unsigned short bb = 0xFFFFu;
    u32 pw = 0;
    if (e < E) {
      const long long eb = 3LL * e;
      const int n0 = __builtin_nontemporal_load(&ntypes[eb]);
      const int n1 = __builtin_nontemporal_load(&ntypes[eb + 1]);
      const int n2 = __builtin_nontemporal_load(&ntypes[eb + 2]);
      if ((n0 | n1 | n2) >= 0) {
        const u32 t = (u32)__builtin_nontemporal_load(&tgt_ids[e]);
        const u32 s = (u32)__builtin_nontemporal_load(&src_ids[e]);
        bb = (unsigned short)(t >> BSH);
        pw = (s << BSH) | (t & (BKT - 1u));
        atomicAdd(&s_cnt[bb], 1u);
      }
    }
    s_b[i] = bb;
    s_pw[i] = pw;
  }
  __syncthreads();

  for (int j = threadIdx.x; j < NB; j += BIN_THREADS) {
    const u32 c = s_cnt[j];
    s_base[j] = c ? atomicAdd(&bcur[j], c) : 0u;
    s_cnt[j] = 0;
  }
  __syncthreads();

  for (int k = 0; k < BIN_TILE / BIN_THREADS; ++k) {
    const int i = threadIdx.x + k * BIN_THREADS;
    const unsigned short bb = s_b[i];
    if (bb != 0xFFFFu) {
      const u32 loc = atomicAdd(&s_cnt[bb], 1u);
      const u32 slot = s_base[bb] + loc;
      if (slot < ((u32)bb + 1u) * (u32)CAP) pairs[slot] = s_pw[i];  // cached
    }
  }
}

// LDS: 35KB + 35KB + 4KB + 4KB + wt -> ~78KB -> 2 blocks/CU (32 waves).
__global__ __launch_bounds__(1024, 8) void sort_gather_kernel(
    const float* __restrict__ feat, const u32* __restrict__ pairs,
    const u32* __restrict__ bcur, float* __restrict__ out, int n_tgt) {
  __shared__ u32 s_pw[CAP];   // staged window
  __shared__ u32 s_srt[CAP];  // src ids sorted by local target
  __shared__ u32 s_cnt[BKT];  // hist, then scatter cursors
  __shared__ u32 s_off[BKT];  // inclusive scan (preserved for gather)
  __shared__ u32 s_wt[16];    // wave totals for shuffle scan
  const int b = blockIdx.x;
  const u32 wbeg = (u32)b * (u32)CAP;
  u32 fill = bcur[b] - wbeg;
  if (fill > (u32)CAP) fill = (u32)CAP;

  for (u32 i = threadIdx.x; i < fill; i += 1024)
    s_pw[i] = __builtin_nontemporal_load(&pairs[wbeg + i]);  // stream-once
  s_cnt[threadIdx.x] = 0;  // blockDim == BKT
  __syncthreads();
  for (u32 i = threadIdx.x; i < fill; i += 1024)
    atomicAdd(&s_cnt[s_pw[i] & (BKT - 1u)], 1u);
  __syncthreads();

  // inclusive scan of s_cnt via wave shuffles: 3 barriers total
  const u32 lane = threadIdx.x & 63u;
  const u32 wid = threadIdx.x >> 6;  // 16 waves
  const u32 v = s_cnt[threadIdx.x];
  u32 x = v;
#pragma unroll
  for (int d = 1; d < 64; d <<= 1) {
    const u32 y = __shfl_up(x, d, 64);
    if (lane >= (u32)d) x += y;
  }
  if (lane == 63u) s_wt[wid] = x;
  __syncthreads();
  if (wid == 0) {
    u32 w = (lane < 16u) ? s_wt[lane] : 0u;
#pragma unroll
    for (int d = 1; d < 16; d <<= 1) {
      const u32 y = __shfl_up(w, d, 64);
      if (lane >= (u32)d) w += y;
    }
    if (lane < 16u) s_wt[lane] = w;
  }
  __syncthreads();
  const u32 incl = x + (wid ? s_wt[wid - 1] : 0u);
  s_off[threadIdx.x] = incl;
  s_cnt[threadIdx.x] = incl - v;  // cursors = exclusive scan
  __syncthreads();

  for (u32 i = threadIdx.x; i < fill; i += 1024) {
    const u32 pw = s_pw[i];
    const u32 loc = atomicAdd(&s_cnt[pw & (BKT - 1u)], 1u);
    s_srt[loc] = pw >> BSH;
  }
  __syncthreads();

  const int grp = threadIdx.x >> 3;  // 0..127
  const int l4 = (threadIdx.x & 7) * 4;  // 4 channels each
  const long long t0 = (long long)b << BSH;
  for (int r = grp; r < BKT; r += 128) {
    const long long t = t0 + r;
    if (t >= n_tgt) break;
    const u32 beg = r ? s_off[r - 1] : 0u;
    const u32 n = s_off[r] - beg;
    f32x4 acc = {0.f, 0.f, 0.f, 0.f};
    for (u32 c = 0; c < n; c += 8) {
      const u32 m = n - c;  // >= 1
      u32 idx[8];
#pragma unroll
      for (int k = 0; k < 8; ++k)
        idx[k] = s_srt[beg + c + ((u32)k < m ? (u32)k : 0u)];
      f32x4 vv[8];
#pragma unroll
      for (int k = 0; k < 8; ++k)
        vv[k] = *reinterpret_cast<const f32x4*>(feat +
                                                (long long)idx[k] * CCH + l4);
#pragma unroll
      for (int k = 0; k < 8; ++k) {
        const float w = ((u32)k < m) ? 1.0f : 0.0f;
        acc += vv[k] * w;
      }
    }
    const float inv = n ? 1.0f / (float)n : 0.0f;
    acc *= inv;
    // 8 lanes x 16B = one full 128B row: full-line nt store (R8-safe)
    __builtin_nontemporal_store(acc,
                                reinterpret_cast<f32x4*>(out + t * CCH + l4));
  }
}

// ---------------- fallback: R1 atomic path ----------------

__global__ __launch_bounds__(256) void scatter_accum_kernel(
    const float* __restrict__ feat, const int* __restrict__ src_ids,
    const int* __restrict__ tgt_ids, const int* __restrict__ ntypes,
    float* __restrict__ sums, u32* __restrict__ counts,
    long long total_threads) {
  long long tid = (long long)blockIdx.x * blockDim.x + threadIdx.x;
  if (tid >= total_threads) return;
  const int e = (int)(tid >> 3);
  const int g = (int)(tid & 7);
  const long long eb = 3LL * e;
  if ((ntypes[eb] | ntypes[eb + 1] | ntypes[eb + 2]) < 0) return;
  const int s = src_ids[e];
  const int t = tgt_ids[e];
  const float4 v =
      *reinterpret_cast<const float4*>(feat + (long long)s * CCH + g * 4);
  float* dst = sums + (long long)t * CCH + g * 4;
  atomicAdd(dst + 0, v.x);
  atomicAdd(dst + 1, v.y);
  atomicAdd(dst + 2, v.z);
  atomicAdd(dst + 3, v.w);
  if (g == 0) atomicAdd(counts + t, 1u);
}

__global__ __launch_bounds__(256) void finalize_kernel(
    float* __restrict__ out, const u32* __restrict__ counts, int total_vec4) {
  int tid = blockIdx.x * blockDim.x + threadIdx.x;
  if (tid >= total_vec4) return;
  const int t = tid >> 3;
  const u32 cnt = counts[t];
  float4* p = reinterpret_cast<float4*>(out) + tid;
  float4 v = *p;
  const float inv = (cnt > 0u) ? (1.0f / (float)cnt) : 0.0f;
  v.x *= inv; v.y *= inv; v.z *= inv; v.w *= inv;
  *p = v;
}

// ---------------- launch ----------------

extern "C" void kernel_launch(void* const* d_in, const int* in_sizes, int n_in,
                              void* d_out, int out_size, void* d_ws,
                              size_t ws_size, hipStream_t stream) {
  const float* feat    = (const float*)d_in[0];
  const int*   src_ids = (const int*)d_in[1];
  const int*   tgt_ids = (const int*)d_in[2];
  const int*   ntypes  = (const int*)d_in[3];
  const int E     = in_sizes[1];
  const int n_src = in_sizes[0] / CCH;
  const int n_tgt = out_size / CCH;

  const int NB = (n_tgt + BKT - 1) >> BSH;

  // ws layout (u32): pairs windows [NB*CAP] | bcur[NB]
  const size_t need = ((size_t)NB * CAP + NB) * sizeof(u32);
  // per-bucket mean fill (unmasked upper bound) must leave sigma headroom
  const long long mean_fill = ((long long)E * BKT + n_tgt - 1) / n_tgt;
  const bool shapes_ok =
      NB <= 2048 && n_src <= (1 << 21) && mean_fill <= 8192;

  if (ws_size >= need && shapes_ok) {
    u32* pairs = (u32*)d_ws;
    u32* bcur  = pairs + (size_t)NB * CAP;

    init_bcur_kernel<<<(NB + 255) / 256, 256, 0, stream>>>(bcur, NB);
    const int bblocks = (E + BIN_TILE - 1) / BIN_TILE;
    bin_fixed_kernel<<<bblocks, BIN_THREADS, 0, stream>>>(
        src_ids, tgt_ids, ntypes, bcur, pairs, E, NB);
    sort_gather_kernel<<<NB, 1024, 0, stream>>>(feat, pairs, bcur,
                                                (float*)d_out, n_tgt);
  } else {
    float* sums   = (float*)d_out;
    u32*   counts = (u32*)d_ws;
    hipMemsetAsync(d_out, 0, (size_t)out_size * sizeof(float), stream);
    hipMemsetAsync(d_ws, 0, (size_t)n_tgt * sizeof(u32), stream);
    const long long total_threads = (long long)E * 8;
    const long long nblocks = (total_threads + 255) / 256;
    scatter_accum_kernel<<<(dim3)((unsigned int)nblocks), 256, 0, stream>>>(
        feat, src_ids, tgt_ids, ntypes, sums, counts, total_threads);
    const int total_vec4 = n_tgt * 8;
    finalize_kernel<<<(total_vec4 + 255) / 256, 256, 0, stream>>>(
        sums, counts, total_vec4);
  }
}

// Round 12
// 268.143 us; speedup vs baseline: 1.0385x; 1.0385x over previous
//
#include <hip/hip_runtime.h>

// Masked scatter-mean, 3-kernel pipeline (no float atomics anywhere).
// R12: bin back to 1024thr/TILE8192 (R11's 512thr regressed: 2x bcur atomics,
// shorter write runs). Bin LDS cut 64->52KB (s_base folded into s_cnt, hist
// arrays 1024 entries) -> 3 blocks/CU. nt out-store dropped (R11: null).
//   init_bcur   : bcur[b] = b*CAP
//   bin_fixed   : ONE edge pass (nt loads); LDS hist; reserve ranges writing
//                 base into s_cnt; scattered cached writes of packed pairs
//   sort_gather : per-bucket LDS sort (shuffle scan) + predicated 8-deep
//                 register gather; plain cached feat/out accesses
// Fallback: R1 atomic path if ws too small / shapes out of range.

#define CCH 32
#define BSH 10            // 1024 targets per bucket
#define BKT 1024
#define CAP 8960          // slots per bucket window (mean fill ~7373, +18 sigma)
#define BIN_TILE 8192
typedef unsigned int u32;
typedef float f32x4 __attribute__((ext_vector_type(4)));

__global__ __launch_bounds__(256) void init_bcur_kernel(u32* __restrict__ bcur,
                                                        int NB) {
  int i = blockIdx.x * 256 + threadIdx.x;
  if (i < NB) bcur[i] = (u32)i * (u32)CAP;
}

// LDS: s_b 16KB + s_pw 32KB + s_cnt 4KB = 52KB -> 3 blocks/CU.
__global__ __launch_bounds__(1024) void bin_fixed_kernel(
    const int* __restrict__ src_ids, const int* __restrict__ tgt_ids,
    const int* __restrict__ ntypes, u32* __restrict__ bcur,
    u32* __restrict__ pairs, int E, int NB) {
  __shared__ unsigned short s_b[BIN_TILE];  // bucket id (0xFFFF = invalid)
  __shared__ u32 s_pw[BIN_TILE];            // packed (src<<10 | local_tgt)
  __shared__ u32 s_cnt[1024];               // hist, then global-slot cursors
  const long long base = (long long)blockIdx.x * BIN_TILE;

  s_cnt[threadIdx.x] = 0;  // blockDim == 1024
  __syncthreads();

  // merged load + histogram pass (nt loads: stream-once edge data)
  for (int k = 0; k < BIN_TILE / 1024; ++k) {
    const int i = threadIdx.x + k * 1024;
    const long long e = base + i;
    unsigned short bb = 0xFFFFu;
    u32 pw = 0;
    if (e < E) {
      const long long eb = 3LL * e;
      const int n0 = __builtin_nontemporal_load(&ntypes[eb]);
      const int n1 = __builtin_nontemporal_load(&ntypes[eb + 1]);
      const int n2 = __builtin_nontemporal_load(&ntypes[eb + 2]);
      if ((n0 | n1 | n2) >= 0) {
        const u32 t = (u32)__builtin_nontemporal_load(&tgt_ids[e]);
        const u32 s = (u32)__builtin_nontemporal_load(&src_ids[e]);
        bb = (unsigned short)(t >> BSH);
        pw = (s << BSH) | (t & (BKT - 1u));
        atomicAdd(&s_cnt[bb], 1u);
      }
    }
    s_b[i] = bb;
    s_pw[i] = pw;
  }
  __syncthreads();

  // reserve: fold global base into s_cnt (cursor = global slot index)
  if ((int)threadIdx.x < NB) {
    const u32 c = s_cnt[threadIdx.x];
    s_cnt[threadIdx.x] = c ? atomicAdd(&bcur[threadIdx.x], c) : 0u;
  }
  __syncthreads();

  for (int k = 0; k < BIN_TILE / 1024; ++k) {
    const int i = threadIdx.x + k * 1024;
    const unsigned short bb = s_b[i];
    if (bb != 0xFFFFu) {
      const u32 slot = atomicAdd(&s_cnt[bb], 1u);
      if (slot < ((u32)bb + 1u) * (u32)CAP) pairs[slot] = s_pw[i];  // clamp
    }
  }
}

// LDS: 35KB + 35KB + 4KB + 4KB + wt -> ~78KB -> 2 blocks/CU (32 waves).
__global__ __launch_bounds__(1024, 8) void sort_gather_kernel(
    const float* __restrict__ feat, const u32* __restrict__ pairs,
    const u32* __restrict__ bcur, float* __restrict__ out, int n_tgt) {
  __shared__ u32 s_pw[CAP];   // staged window
  __shared__ u32 s_srt[CAP];  // src ids sorted by local target
  __shared__ u32 s_cnt[BKT];  // hist, then scatter cursors
  __shared__ u32 s_off[BKT];  // inclusive scan (preserved for gather)
  __shared__ u32 s_wt[16];    // wave totals for shuffle scan
  const int b = blockIdx.x;
  const u32 wbeg = (u32)b * (u32)CAP;
  u32 fill = bcur[b] - wbeg;
  if (fill > (u32)CAP) fill = (u32)CAP;

  for (u32 i = threadIdx.x; i < fill; i += 1024)
    s_pw[i] = __builtin_nontemporal_load(&pairs[wbeg + i]);  // stream-once
  s_cnt[threadIdx.x] = 0;  // blockDim == BKT
  __syncthreads();
  for (u32 i = threadIdx.x; i < fill; i += 1024)
    atomicAdd(&s_cnt[s_pw[i] & (BKT - 1u)], 1u);
  __syncthreads();

  // inclusive scan of s_cnt via wave shuffles: 3 barriers total
  const u32 lane = threadIdx.x & 63u;
  const u32 wid = threadIdx.x >> 6;  // 16 waves
  const u32 v = s_cnt[threadIdx.x];
  u32 x = v;
#pragma unroll
  for (int d = 1; d < 64; d <<= 1) {
    const u32 y = __shfl_up(x, d, 64);
    if (lane >= (u32)d) x += y;
  }
  if (lane == 63u) s_wt[wid] = x;
  __syncthreads();
  if (wid == 0) {
    u32 w = (lane < 16u) ? s_wt[lane] : 0u;
#pragma unroll
    for (int d = 1; d < 16; d <<= 1) {
      const u32 y = __shfl_up(w, d, 64);
      if (lane >= (u32)d) w += y;
    }
    if (lane < 16u) s_wt[lane] = w;
  }
  __syncthreads();
  const u32 incl = x + (wid ? s_wt[wid - 1] : 0u);
  s_off[threadIdx.x] = incl;
  s_cnt[threadIdx.x] = incl - v;  // cursors = exclusive scan
  __syncthreads();

  for (u32 i = threadIdx.x; i < fill; i += 1024) {
    const u32 pw = s_pw[i];
    const u32 loc = atomicAdd(&s_cnt[pw & (BKT - 1u)], 1u);
    s_srt[loc] = pw >> BSH;
  }
  __syncthreads();

  const int grp = threadIdx.x >> 3;  // 0..127
  const int l4 = (threadIdx.x & 7) * 4;  // 4 channels each
  const long long t0 = (long long)b << BSH;
  for (int r = grp; r < BKT; r += 128) {
    const long long t = t0 + r;
    if (t >= n_tgt) break;
    const u32 beg = r ? s_off[r - 1] : 0u;
    const u32 n = s_off[r] - beg;
    f32x4 acc = {0.f, 0.f, 0.f, 0.f};
    for (u32 c = 0; c < n; c += 8) {
      const u32 m = n - c;  // >= 1
      u32 idx[8];
#pragma unroll
      for (int k = 0; k < 8; ++k)
        idx[k] = s_srt[beg + c + ((u32)k < m ? (u32)k : 0u)];
      f32x4 vv[8];
#pragma unroll
      for (int k = 0; k < 8; ++k)
        vv[k] = *reinterpret_cast<const f32x4*>(feat +
                                                (long long)idx[k] * CCH + l4);
#pragma unroll
      for (int k = 0; k < 8; ++k) {
        const float w = ((u32)k < m) ? 1.0f : 0.0f;
        acc += vv[k] * w;
      }
    }
    const float inv = n ? 1.0f / (float)n : 0.0f;
    acc *= inv;
    *reinterpret_cast<f32x4*>(out + t * CCH + l4) = acc;
  }
}

// ---------------- fallback: R1 atomic path ----------------

__global__ __launch_bounds__(256) void scatter_accum_kernel(
    const float* __restrict__ feat, const int* __restrict__ src_ids,
    const int* __restrict__ tgt_ids, const int* __restrict__ ntypes,
    float* __restrict__ sums, u32* __restrict__ counts,
    long long total_threads) {
  long long tid = (long long)blockIdx.x * blockDim.x + threadIdx.x;
  if (tid >= total_threads) return;
  const int e = (int)(tid >> 3);
  const int g = (int)(tid & 7);
  const long long eb = 3LL * e;
  if ((ntypes[eb] | ntypes[eb + 1] | ntypes[eb + 2]) < 0) return;
  const int s = src_ids[e];
  const int t = tgt_ids[e];
  const float4 v =
      *reinterpret_cast<const float4*>(feat + (long long)s * CCH + g * 4);
  float* dst = sums + (long long)t * CCH + g * 4;
  atomicAdd(dst + 0, v.x);
  atomicAdd(dst + 1, v.y);
  atomicAdd(dst + 2, v.z);
  atomicAdd(dst + 3, v.w);
  if (g == 0) atomicAdd(counts + t, 1u);
}

__global__ __launch_bounds__(256) void finalize_kernel(
    float* __restrict__ out, const u32* __restrict__ counts, int total_vec4) {
  int tid = blockIdx.x * blockDim.x + threadIdx.x;
  if (tid >= total_vec4) return;
  const int t = tid >> 3;
  const u32 cnt = counts[t];
  float4* p = reinterpret_cast<float4*>(out) + tid;
  float4 v = *p;
  const float inv = (cnt > 0u) ? (1.0f / (float)cnt) : 0.0f;
  v.x *= inv; v.y *= inv; v.z *= inv; v.w *= inv;
  *p = v;
}

// ---------------- launch ----------------

extern "C" void kernel_launch(void* const* d_in, const int* in_sizes, int n_in,
                              void* d_out, int out_size, void* d_ws,
                              size_t ws_size, hipStream_t stream) {
  const float* feat    = (const float*)d_in[0];
  const int*   src_ids = (const int*)d_in[1];
  const int*   tgt_ids = (const int*)d_in[2];
  const int*   ntypes  = (const int*)d_in[3];
  const int E     = in_sizes[1];
  const int n_src = in_sizes[0] / CCH;
  const int n_tgt = out_size / CCH;

  const int NB = (n_tgt + BKT - 1) >> BSH;

  // ws layout (u32): pairs windows [NB*CAP] | bcur[NB]
  const size_t need = ((size_t)NB * CAP + NB) * sizeof(u32);
  // per-bucket mean fill (unmasked upper bound) must leave sigma headroom
  const long long mean_fill = ((long long)E * BKT + n_tgt - 1) / n_tgt;
  const bool shapes_ok =
      NB <= 1024 && n_src <= (1 << 21) && mean_fill <= 8192;

  if (ws_size >= need && shapes_ok) {
    u32* pairs = (u32*)d_ws;
    u32* bcur  = pairs + (size_t)NB * CAP;

    init_bcur_kernel<<<(NB + 255) / 256, 256, 0, stream>>>(bcur, NB);
    const int bblocks = (E + BIN_TILE - 1) / BIN_TILE;
    bin_fixed_kernel<<<bblocks, 1024, 0, stream>>>(src_ids, tgt_ids, ntypes,
                                                   bcur, pairs, E, NB);
    sort_gather_kernel<<<NB, 1024, 0, stream>>>(feat, pairs, bcur,
                                                (float*)d_out, n_tgt);
  } else {
    float* sums   = (float*)d_out;
    u32*   counts = (u32*)d_ws;
    hipMemsetAsync(d_out, 0, (size_t)out_size * sizeof(float), stream);
    hipMemsetAsync(d_ws, 0, (size_t)n_tgt * sizeof(u32), stream);
    const long long total_threads = (long long)E * 8;
    const long long nblocks = (total_threads + 255) / 256;
    scatter_accum_kernel<<<(dim3)((unsigned int)nblocks), 256, 0, stream>>>(
        feat, src_ids, tgt_ids, ntypes, sums, counts, total_threads);
    const int total_vec4 = n_tgt * 8;
    finalize_kernel<<<(total_vec4 + 255) / 256, 256, 0, stream>>>(
        sums, counts, total_vec4);
  }
}

// Round 13
// 256.732 us; speedup vs baseline: 1.0847x; 1.0444x over previous
//
#include <hip/hip_runtime.h>

// Masked scatter-mean, 2-kernel pipeline + 1 memset (no float atomics).
// R13: bin edge loads vectorized 4-edges/thread (3x int4 ntypes + int4 tgt +
// int4 src = 5 coalesced 16B loads per 4 edges, was 20 scalar stride-12);
// bcur cursors window-relative (memset replaces init kernel).
//   bin_fixed   : ONE edge pass; LDS hist; reserve ranges (relative); cached
//                 scattered writes of packed (src<<10 | tgt&1023)
//   sort_gather : per-bucket LDS sort (shuffle scan) + predicated 8-deep
//                 register gather; plain cached feat/out accesses
// Fallback: R1 atomic path if ws too small / shapes out of range.

#define CCH 32
#define BSH 10            // 1024 targets per bucket
#define BKT 1024
#define CAP 8960          // slots per bucket window (mean fill ~7373, +18 sigma)
#define BIN_TILE 8192
typedef unsigned int u32;
typedef float f32x4 __attribute__((ext_vector_type(4)));
typedef int i32x4 __attribute__((ext_vector_type(4)));

// LDS: s_b 16KB + s_pw 32KB + s_cnt 4KB = 52KB (2 blocks/CU via thread cap).
__global__ __launch_bounds__(1024) void bin_fixed_kernel(
    const int* __restrict__ src_ids, const int* __restrict__ tgt_ids,
    const int* __restrict__ ntypes, u32* __restrict__ bcur,
    u32* __restrict__ pairs, int E, int NB) {
  __shared__ unsigned short s_b[BIN_TILE];  // bucket id (0xFFFF = invalid)
  __shared__ u32 s_pw[BIN_TILE];            // packed (src<<10 | local_tgt)
  __shared__ u32 s_cnt[1024];               // hist, then relative cursors
  const long long base = (long long)blockIdx.x * BIN_TILE;

  s_cnt[threadIdx.x] = 0;  // blockDim == 1024
  __syncthreads();

  // merged load + histogram pass: 4 edges per thread per k (vectorized)
  for (int k = 0; k < BIN_TILE / 4096; ++k) {
    const int i4 = (threadIdx.x + k * 1024) * 4;  // tile-local edge base
    const long long e4 = base + i4;
    int n_or[4];
    int tg[4], sr[4];
    bool any = false;
    if (e4 + 3 < E) {
      const i32x4 w0 = __builtin_nontemporal_load(
          reinterpret_cast<const i32x4*>(ntypes + 3 * e4));
      const i32x4 w1 = __builtin_nontemporal_load(
          reinterpret_cast<const i32x4*>(ntypes + 3 * e4 + 4));
      const i32x4 w2 = __builtin_nontemporal_load(
          reinterpret_cast<const i32x4*>(ntypes + 3 * e4 + 8));
      const i32x4 t4 = __builtin_nontemporal_load(
          reinterpret_cast<const i32x4*>(tgt_ids + e4));
      const i32x4 s4 = __builtin_nontemporal_load(
          reinterpret_cast<const i32x4*>(src_ids + e4));
      n_or[0] = w0.x | w0.y | w0.z;
      n_or[1] = w0.w | w1.x | w1.y;
      n_or[2] = w1.z | w1.w | w2.x;
      n_or[3] = w2.y | w2.z | w2.w;
      tg[0] = t4.x; tg[1] = t4.y; tg[2] = t4.z; tg[3] = t4.w;
      sr[0] = s4.x; sr[1] = s4.y; sr[2] = s4.z; sr[3] = s4.w;
      any = true;
    } else {
#pragma unroll
      for (int j = 0; j < 4; ++j) {
        const long long e = e4 + j;
        if (e < E) {
          const long long eb = 3LL * e;
          n_or[j] = ntypes[eb] | ntypes[eb + 1] | ntypes[eb + 2];
          tg[j] = tgt_ids[e];
          sr[j] = src_ids[e];
          any = true;
        } else {
          n_or[j] = -1;
        }
      }
    }
#pragma unroll
    for (int j = 0; j < 4; ++j) {
      unsigned short bb = 0xFFFFu;
      u32 pw = 0;
      if (any && n_or[j] >= 0) {
        const u32 t = (u32)tg[j];
        bb = (unsigned short)(t >> BSH);
        pw = ((u32)sr[j] << BSH) | (t & (BKT - 1u));
        atomicAdd(&s_cnt[bb], 1u);
      }
      s_b[i4 + j] = bb;
      s_pw[i4 + j] = pw;
    }
  }
  __syncthreads();

  // reserve: window-relative base into s_cnt
  if ((int)threadIdx.x < NB) {
    const u32 c = s_cnt[threadIdx.x];
    s_cnt[threadIdx.x] = c ? atomicAdd(&bcur[threadIdx.x], c) : 0u;
  }
  __syncthreads();

  for (int k = 0; k < BIN_TILE / 1024; ++k) {
    const int i = threadIdx.x + k * 1024;
    const unsigned short bb = s_b[i];
    if (bb != 0xFFFFu) {
      const u32 loc = atomicAdd(&s_cnt[bb], 1u);
      if (loc < (u32)CAP) pairs[(u32)bb * (u32)CAP + loc] = s_pw[i];  // clamp
    }
  }
}

// LDS: 35KB + 35KB + 4KB + 4KB + wt -> ~78KB -> 2 blocks/CU (32 waves).
__global__ __launch_bounds__(1024, 8) void sort_gather_kernel(
    const float* __restrict__ feat, const u32* __restrict__ pairs,
    const u32* __restrict__ bcur, float* __restrict__ out, int n_tgt) {
  __shared__ u32 s_pw[CAP];   // staged window
  __shared__ u32 s_srt[CAP];  // src ids sorted by local target
  __shared__ u32 s_cnt[BKT];  // hist, then scatter cursors
  __shared__ u32 s_off[BKT];  // inclusive scan (preserved for gather)
  __shared__ u32 s_wt[16];    // wave totals for shuffle scan
  const int b = blockIdx.x;
  const u32 wbeg = (u32)b * (u32)CAP;
  u32 fill = bcur[b];  // window-relative
  if (fill > (u32)CAP) fill = (u32)CAP;

  for (u32 i = threadIdx.x; i < fill; i += 1024)
    s_pw[i] = __builtin_nontemporal_load(&pairs[wbeg + i]);  // stream-once
  s_cnt[threadIdx.x] = 0;  // blockDim == BKT
  __syncthreads();
  for (u32 i = threadIdx.x; i < fill; i += 1024)
    atomicAdd(&s_cnt[s_pw[i] & (BKT - 1u)], 1u);
  __syncthreads();

  // inclusive scan of s_cnt via wave shuffles: 3 barriers total
  const u32 lane = threadIdx.x & 63u;
  const u32 wid = threadIdx.x >> 6;  // 16 waves
  const u32 v = s_cnt[threadIdx.x];
  u32 x = v;
#pragma unroll
  for (int d = 1; d < 64; d <<= 1) {
    const u32 y = __shfl_up(x, d, 64);
    if (lane >= (u32)d) x += y;
  }
  if (lane == 63u) s_wt[wid] = x;
  __syncthreads();
  if (wid == 0) {
    u32 w = (lane < 16u) ? s_wt[lane] : 0u;
#pragma unroll
    for (int d = 1; d < 16; d <<= 1) {
      const u32 y = __shfl_up(w, d, 64);
      if (lane >= (u32)d) w += y;
    }
    if (lane < 16u) s_wt[lane] = w;
  }
  __syncthreads();
  const u32 incl = x + (wid ? s_wt[wid - 1] : 0u);
  s_off[threadIdx.x] = incl;
  s_cnt[threadIdx.x] = incl - v;  // cursors = exclusive scan
  __syncthreads();

  for (u32 i = threadIdx.x; i < fill; i += 1024) {
    const u32 pw = s_pw[i];
    const u32 loc = atomicAdd(&s_cnt[pw & (BKT - 1u)], 1u);
    s_srt[loc] = pw >> BSH;
  }
  __syncthreads();

  const int grp = threadIdx.x >> 3;  // 0..127
  const int l4 = (threadIdx.x & 7) * 4;  // 4 channels each
  const long long t0 = (long long)b << BSH;
  for (int r = grp; r < BKT; r += 128) {
    const long long t = t0 + r;
    if (t >= n_tgt) break;
    const u32 beg = r ? s_off[r - 1] : 0u;
    const u32 n = s_off[r] - beg;
    f32x4 acc = {0.f, 0.f, 0.f, 0.f};
    for (u32 c = 0; c < n; c += 8) {
      const u32 m = n - c;  // >= 1
      u32 idx[8];
#pragma unroll
      for (int k = 0; k < 8; ++k)
        idx[k] = s_srt[beg + c + ((u32)k < m ? (u32)k : 0u)];
      f32x4 vv[8];
#pragma unroll
      for (int k = 0; k < 8; ++k)
        vv[k] = *reinterpret_cast<const f32x4*>(feat +
                                                (long long)idx[k] * CCH + l4);
#pragma unroll
      for (int k = 0; k < 8; ++k) {
        const float w = ((u32)k < m) ? 1.0f : 0.0f;
        acc += vv[k] * w;
      }
    }
    const float inv = n ? 1.0f / (float)n : 0.0f;
    acc *= inv;
    *reinterpret_cast<f32x4*>(out + t * CCH + l4) = acc;
  }
}

// ---------------- fallback: R1 atomic path ----------------

__global__ __launch_bounds__(256) void scatter_accum_kernel(
    const float* __restrict__ feat, const int* __restrict__ src_ids,
    const int* __restrict__ tgt_ids, const int* __restrict__ ntypes,
    float* __restrict__ sums, u32* __restrict__ counts,
    long long total_threads) {
  long long tid = (long long)blockIdx.x * blockDim.x + threadIdx.x;
  if (tid >= total_threads) return;
  const int e = (int)(tid >> 3);
  const int g = (int)(tid & 7);
  const long long eb = 3LL * e;
  if ((ntypes[eb] | ntypes[eb + 1] | ntypes[eb + 2]) < 0) return;
  const int s = src_ids[e];
  const int t = tgt_ids[e];
  const float4 v =
      *reinterpret_cast<const float4*>(feat + (long long)s * CCH + g * 4);
  float* dst = sums + (long long)t * CCH + g * 4;
  atomicAdd(dst + 0, v.x);
  atomicAdd(dst + 1, v.y);
  atomicAdd(dst + 2, v.z);
  atomicAdd(dst + 3, v.w);
  if (g == 0) atomicAdd(counts + t, 1u);
}

__global__ __launch_bounds__(256) void finalize_kernel(
    float* __restrict__ out, const u32* __restrict__ counts, int total_vec4) {
  int tid = blockIdx.x * blockDim.x + threadIdx.x;
  if (tid >= total_vec4) return;
  const int t = tid >> 3;
  const u32 cnt = counts[t];
  float4* p = reinterpret_cast<float4*>(out) + tid;
  float4 v = *p;
  const float inv = (cnt > 0u) ? (1.0f / (float)cnt) : 0.0f;
  v.x *= inv; v.y *= inv; v.z *= inv; v.w *= inv;
  *p = v;
}

// ---------------- launch ----------------

extern "C" void kernel_launch(void* const* d_in, const int* in_sizes, int n_in,
                              void* d_out, int out_size, void* d_ws,
                              size_t ws_size, hipStream_t stream) {
  const float* feat    = (const float*)d_in[0];
  const int*   src_ids = (const int*)d_in[1];
  const int*   tgt_ids = (const int*)d_in[2];
  const int*   ntypes  = (const int*)d_in[3];
  const int E     = in_sizes[1];
  const int n_src = in_sizes[0] / CCH;
  const int n_tgt = out_size / CCH;

  const int NB = (n_tgt + BKT - 1) >> BSH;

  // ws layout (u32): pairs windows [NB*CAP] | bcur[NB]
  const size_t need = ((size_t)NB * CAP + NB) * sizeof(u32);
  // per-bucket mean fill (unmasked upper bound) must leave sigma headroom
  const long long mean_fill = ((long long)E * BKT + n_tgt - 1) / n_tgt;
  const bool shapes_ok =
      NB <= 1024 && n_src <= (1 << 21) && mean_fill <= 8192;

  if (ws_size >= need && shapes_ok) {
    u32* pairs = (u32*)d_ws;
    u32* bcur  = pairs + (size_t)NB * CAP;

    hipMemsetAsync(bcur, 0, (size_t)NB * sizeof(u32), stream);
    const int bblocks = (E + BIN_TILE - 1) / BIN_TILE;
    bin_fixed_kernel<<<bblocks, 1024, 0, stream>>>(src_ids, tgt_ids, ntypes,
                                                   bcur, pairs, E, NB);
    sort_gather_kernel<<<NB, 1024, 0, stream>>>(feat, pairs, bcur,
                                                (float*)d_out, n_tgt);
  } else {
    float* sums   = (float*)d_out;
    u32*   counts = (u32*)d_ws;
    hipMemsetAsync(d_out, 0, (size_t)out_size * sizeof(float), stream);
    hipMemsetAsync(d_ws, 0, (size_t)n_tgt * sizeof(u32), stream);
    const long long total_threads = (long long)E * 8;
    const long long nblocks = (total_threads + 255) / 256;
    scatter_accum_kernel<<<(dim3)((unsigned int)nblocks), 256, 0, stream>>>(
        feat, src_ids, tgt_ids, ntypes, sums, counts, total_threads);
    const int total_vec4 = n_tgt * 8;
    finalize_kernel<<<(total_vec4 + 255) / 256, 256, 0, stream>>>(
        sums, counts, total_vec4);
  }
}